// Round 1
// baseline (531.282 us; speedup 1.0000x reference)
//
#include <hip/hip_runtime.h>
#include <hip/hip_bf16.h>

// Problem dims (fixed)
#define MROWS 8192      // B*T
#define HIDD  512
#define KD    256
#define VDIM  512
#define NH    4
#define HK    64
#define HV    128
#define TSEQ  2048
#define BATCH 4
#define NC    32        // number of chunks
#define CHK   64        // chunk length
#define LDP   1536      // proj row stride: q[0,256) k[256,512) v[512,1024) g[1024,1536)

// ---------------------------------------------------------------------------
// Generic fp32 GEMM: C[M,N] = A[M,K] @ W[N,K]^T. 128x128 tile, BK=16,
// 256 threads, 8x8 per thread (2x2 blocks of 4x4 at stride 64).
// ---------------------------------------------------------------------------
__global__ __launch_bounds__(256) void gemm_nt_f32(
    const float* __restrict__ A, const float* __restrict__ W,
    float* __restrict__ C, int K, int ldc) {
  __shared__ float As[16][132];
  __shared__ float Bs[16][132];
  const int tid = threadIdx.x;
  const int m0 = blockIdx.x * 128;
  const int n0 = blockIdx.y * 128;
  const int r  = tid >> 2;           // 0..63
  const int kq = (tid & 3) * 4;      // 0,4,8,12
  const int tx = tid & 15;           // n-dir
  const int ty = tid >> 4;           // m-dir
  const float* Aptr = A + (size_t)(m0 + r) * K + kq;
  const float* Wptr = W + (size_t)(n0 + r) * K + kq;
  float acc[2][2][4][4];
#pragma unroll
  for (int a = 0; a < 2; ++a)
#pragma unroll
    for (int b = 0; b < 2; ++b)
#pragma unroll
      for (int i = 0; i < 4; ++i)
#pragma unroll
        for (int j = 0; j < 4; ++j) acc[a][b][i][j] = 0.f;

  for (int k0 = 0; k0 < K; k0 += 16) {
    const float4 a0 = *(const float4*)(Aptr);
    const float4 a1 = *(const float4*)(Aptr + 64 * K);
    const float4 b0 = *(const float4*)(Wptr);
    const float4 b1 = *(const float4*)(Wptr + 64 * K);
    Aptr += 16; Wptr += 16;
    __syncthreads();
    As[kq + 0][r] = a0.x; As[kq + 1][r] = a0.y; As[kq + 2][r] = a0.z; As[kq + 3][r] = a0.w;
    As[kq + 0][r + 64] = a1.x; As[kq + 1][r + 64] = a1.y; As[kq + 2][r + 64] = a1.z; As[kq + 3][r + 64] = a1.w;
    Bs[kq + 0][r] = b0.x; Bs[kq + 1][r] = b0.y; Bs[kq + 2][r] = b0.z; Bs[kq + 3][r] = b0.w;
    Bs[kq + 0][r + 64] = b1.x; Bs[kq + 1][r + 64] = b1.y; Bs[kq + 2][r + 64] = b1.z; Bs[kq + 3][r + 64] = b1.w;
    __syncthreads();
#pragma unroll
    for (int kk = 0; kk < 16; ++kk) {
      const float4 av0 = *(const float4*)&As[kk][ty * 4];
      const float4 av1 = *(const float4*)&As[kk][ty * 4 + 64];
      const float4 bv0 = *(const float4*)&Bs[kk][tx * 4];
      const float4 bv1 = *(const float4*)&Bs[kk][tx * 4 + 64];
      const float am[2][4] = {{av0.x, av0.y, av0.z, av0.w}, {av1.x, av1.y, av1.z, av1.w}};
      const float bm[2][4] = {{bv0.x, bv0.y, bv0.z, bv0.w}, {bv1.x, bv1.y, bv1.z, bv1.w}};
#pragma unroll
      for (int ih = 0; ih < 2; ++ih)
#pragma unroll
        for (int i = 0; i < 4; ++i)
#pragma unroll
          for (int jh = 0; jh < 2; ++jh)
#pragma unroll
            for (int j = 0; j < 4; ++j)
              acc[ih][jh][i][j] = fmaf(am[ih][i], bm[jh][j], acc[ih][jh][i][j]);
    }
  }
#pragma unroll
  for (int ih = 0; ih < 2; ++ih)
#pragma unroll
    for (int i = 0; i < 4; ++i) {
      const size_t row = (size_t)(m0 + ih * 64 + ty * 4 + i);
      float* cp = C + row * ldc + n0;
      *(float4*)(cp + tx * 4) =
          make_float4(acc[ih][0][i][0], acc[ih][0][i][1], acc[ih][0][i][2], acc[ih][0][i][3]);
      *(float4*)(cp + 64 + tx * 4) =
          make_float4(acc[ih][1][i][0], acc[ih][1][i][1], acc[ih][1][i][2], acc[ih][1][i][3]);
    }
}

// ---------------------------------------------------------------------------
// g1 = X @ Wgk1^T   [8192,16], K=512. 512 blocks x 256 thr, 1 output/thread.
// ---------------------------------------------------------------------------
__global__ __launch_bounds__(256) void lowrank1(
    const float* __restrict__ X, const float* __restrict__ W1,
    float* __restrict__ g1) {
  const int mrow = blockIdx.x * 16 + (threadIdx.x >> 4);
  const int col  = threadIdx.x & 15;
  const float* x = X + (size_t)mrow * HIDD;
  const float* w = W1 + (size_t)col * HIDD;
  float s = 0.f;
  for (int k = 0; k < HIDD; k += 4) {
    const float4 xv = *(const float4*)(x + k);
    const float4 wv = *(const float4*)(w + k);
    s += xv.x * wv.x + xv.y * wv.y + xv.z * wv.z + xv.w * wv.w;
  }
  g1[(size_t)mrow * 16 + col] = s;
}

// ---------------------------------------------------------------------------
// gdec[m,n] = log_sigmoid(g1[m,:] @ Wgk2[n,:] + b[n]) / 16.   [8192,256]
// ---------------------------------------------------------------------------
__global__ __launch_bounds__(256) void gate_decay(
    const float* __restrict__ g1, const float* __restrict__ W2,
    const float* __restrict__ bias, float* __restrict__ gdec) {
  const int m = blockIdx.x;
  const int n = threadIdx.x;
  const float* gr = g1 + (size_t)m * 16;
  const float* w  = W2 + (size_t)n * 16;
  float s = bias[n];
#pragma unroll
  for (int j4 = 0; j4 < 4; ++j4) {
    const float4 gv = *(const float4*)(gr + j4 * 4);
    const float4 wv = *(const float4*)(w + j4 * 4);
    s += gv.x * wv.x + gv.y * wv.y + gv.z * wv.z + gv.w * wv.w;
  }
  const float t = fabsf(s);
  const float ls = fminf(s, 0.f) - log1pf(expf(-t));
  gdec[(size_t)m * KD + n] = ls * (1.0f / 16.0f);
}

// ---------------------------------------------------------------------------
// Per-chunk summaries: dS[kk,v] = sum_t k[t,kk]*exp(B63[kk]-B_t[kk]) * V[t,v]
//                      dvec[kk] = exp(B63[kk]).   Grid (32,4,4), 256 thr.
// ---------------------------------------------------------------------------
__global__ __launch_bounds__(256) void chunk_summary(
    const float* __restrict__ proj, const float* __restrict__ gdec,
    float* __restrict__ dS, float* __restrict__ dvec) {
  __shared__ float kh[64][68];
  __shared__ float Vs[64 * HV];
  __shared__ float bl[64];
  const int c = blockIdx.x, h = blockIdx.y, b = blockIdx.z;
  const int bh = b * NH + h;
  const int tid = threadIdx.x;
  const size_t rowbase = (size_t)b * TSEQ + (size_t)c * CHK;
  // stage gdec chunk into kh
  for (int base = 0; base < 4096; base += 1024) {
    const int idx = base + tid * 4;
    const int t = idx >> 6, kk = idx & 63;
    *(float4*)&kh[t][kk] = *(const float4*)&gdec[(rowbase + t) * KD + h * HK + kk];
  }
  // stage V chunk
  for (int base = 0; base < 8192; base += 1024) {
    const int idx = base + tid * 4;
    const int t = idx >> 7, v = idx & 127;
    *(float4*)&Vs[t * HV + v] = *(const float4*)&proj[(rowbase + t) * LDP + 2 * KD + h * HV + v];
  }
  __syncthreads();
  if (tid < 64) {
    float s = 0.f;
    for (int t = 0; t < CHK; ++t) { s += kh[t][tid]; kh[t][tid] = s; }
    bl[tid] = s;
    dvec[((size_t)bh * NC + c) * HK + tid] = expf(s);
  }
  __syncthreads();
  // kh[t][kk] = k * exp(B63 - B_t)
  for (int base = 0; base < 4096; base += 1024) {
    const int idx = base + tid * 4;
    const int t = idx >> 6, kk = idx & 63;
    const float4 kv = *(const float4*)&proj[(rowbase + t) * LDP + KD + h * HK + kk];
    const float4 Bv = *(const float4*)&kh[t][kk];
    float4 rv;
    rv.x = kv.x * expf(bl[kk + 0] - Bv.x);
    rv.y = kv.y * expf(bl[kk + 1] - Bv.y);
    rv.z = kv.z * expf(bl[kk + 2] - Bv.z);
    rv.w = kv.w * expf(bl[kk + 3] - Bv.w);
    *(float4*)&kh[t][kk] = rv;
  }
  __syncthreads();
  const int kk = tid & 63;
  const int vg = (tid >> 6) * 32;
  float acc[32];
#pragma unroll
  for (int x = 0; x < 32; ++x) acc[x] = 0.f;
  for (int t = 0; t < CHK; ++t) {
    const float kv = kh[t][kk];
#pragma unroll
    for (int j = 0; j < 32; j += 4) {
      const float4 vv = *(const float4*)&Vs[t * HV + vg + j];
      acc[j + 0] = fmaf(kv, vv.x, acc[j + 0]);
      acc[j + 1] = fmaf(kv, vv.y, acc[j + 1]);
      acc[j + 2] = fmaf(kv, vv.z, acc[j + 2]);
      acc[j + 3] = fmaf(kv, vv.w, acc[j + 3]);
    }
  }
  float* outp = dS + (((size_t)bh * NC + c) * HK + kk) * HV + vg;
#pragma unroll
  for (int j = 0; j < 32; j += 4)
    *(float4*)(outp + j) = make_float4(acc[j], acc[j + 1], acc[j + 2], acc[j + 3]);
}

// ---------------------------------------------------------------------------
// Sequential inter-chunk state propagation. Sall[bh][c] = state at chunk start.
// 16 blocks x 256 threads, 32 chunks serial.
// ---------------------------------------------------------------------------
__global__ __launch_bounds__(256) void state_prop(
    const float* __restrict__ dS, const float* __restrict__ dvec,
    float* __restrict__ Sall) {
  const int bh = blockIdx.x;
  const int tid = threadIdx.x;
  float S[32];
#pragma unroll
  for (int x = 0; x < 32; ++x) S[x] = 0.f;
  for (int cc = 0; cc < NC; ++cc) {
    const size_t base = ((size_t)bh * NC + cc) * (HK * HV);
    const float* dv = dvec + ((size_t)bh * NC + cc) * HK;
#pragma unroll
    for (int x = 0; x < 32; ++x) {
      const int e = x * 256 + tid;
      Sall[base + e] = S[x];
      S[x] = S[x] * dv[e >> 7] + dS[base + e];
    }
  }
}

// ---------------------------------------------------------------------------
// Per-chunk output: o = P@V + (q*scale*e^B)@S_prev, then fused per-head
// RMSNorm * gnorm_w * silu(g). Grid (32,4,4), 256 threads.
// Thread: row i = tid>>2, v-set = {vc*4 + jj*16 + e}, vc = tid&3.
// ---------------------------------------------------------------------------
__global__ __launch_bounds__(256) void chunk_output(
    const float* __restrict__ proj, const float* __restrict__ gdec,
    const float* __restrict__ Sall, const float* __restrict__ gnw,
    float* __restrict__ og) {
  __shared__ float smem[3 * 64 * 68];
  float (*qt)[68] = (float(*)[68])smem;
  float (*kt)[68] = (float(*)[68])(smem + 64 * 68);
  float (*Pm)[68] = (float(*)[68])(smem + 2 * 64 * 68);
  float* Vs = smem;  // [64][128] overlaps qt+kt (8192 <= 8704 floats)
  const int c = blockIdx.x, h = blockIdx.y, b = blockIdx.z;
  const int bh = b * NH + h;
  const int tid = threadIdx.x;
  const size_t rowbase = (size_t)b * TSEQ + (size_t)c * CHK;
  // stage gdec -> Pm (pre-cumsum)
  for (int base = 0; base < 4096; base += 1024) {
    const int idx = base + tid * 4;
    const int t = idx >> 6, kk = idx & 63;
    *(float4*)&Pm[t][kk] = *(const float4*)&gdec[(rowbase + t) * KD + h * HK + kk];
  }
  __syncthreads();
  if (tid < 64) {
    float s = 0.f;
    for (int t = 0; t < CHK; ++t) { s += Pm[t][tid]; Pm[t][tid] = s; }
  }
  __syncthreads();
  // build qt = q*scale*e^B, kt = k*e^{-B}
  for (int base = 0; base < 4096; base += 1024) {
    const int idx = base + tid * 4;
    const int t = idx >> 6, kk = idx & 63;
    const float4 qv = *(const float4*)&proj[(rowbase + t) * LDP + h * HK + kk];
    const float4 kv = *(const float4*)&proj[(rowbase + t) * LDP + KD + h * HK + kk];
    const float4 Bv = *(const float4*)&Pm[t][kk];
    qt[t][kk + 0] = qv.x * 0.125f * expf(Bv.x);
    qt[t][kk + 1] = qv.y * 0.125f * expf(Bv.y);
    qt[t][kk + 2] = qv.z * 0.125f * expf(Bv.z);
    qt[t][kk + 3] = qv.w * 0.125f * expf(Bv.w);
    kt[t][kk + 0] = kv.x * expf(-Bv.x);
    kt[t][kk + 1] = kv.y * expf(-Bv.y);
    kt[t][kk + 2] = kv.z * expf(-Bv.z);
    kt[t][kk + 3] = kv.w * expf(-Bv.w);
  }
  __syncthreads();
  const int i = tid >> 2;
  const int vc = tid & 3;
  // P[i][j] for j = vc + jj*4 (causal-masked, diagonal included)
  float pv[16];
#pragma unroll
  for (int jj = 0; jj < 16; ++jj) pv[jj] = 0.f;
  for (int k0 = 0; k0 < CHK; k0 += 4) {
    const float4 qv = *(const float4*)&qt[i][k0];
#pragma unroll
    for (int jj = 0; jj < 16; ++jj) {
      const int j = vc + jj * 4;
      const float4 kv = *(const float4*)&kt[j][k0];
      pv[jj] += qv.x * kv.x + qv.y * kv.y + qv.z * kv.z + qv.w * kv.w;
    }
  }
#pragma unroll
  for (int jj = 0; jj < 16; ++jj) {
    const int j = vc + jj * 4;
    Pm[i][j] = (j <= i) ? pv[jj] : 0.f;
  }
  // o_inter = qt @ S_prev (S from global, L1-resident)
  float oacc[32];
#pragma unroll
  for (int x = 0; x < 32; ++x) oacc[x] = 0.f;
  const float* Sp = Sall + ((size_t)bh * NC + c) * (HK * HV);
  for (int k = 0; k < HK; ++k) {
    const float qvs = qt[i][k];
#pragma unroll
    for (int jj = 0; jj < 8; ++jj) {
      const float4 sv = *(const float4*)&Sp[k * HV + vc * 4 + jj * 16];
      oacc[jj * 4 + 0] = fmaf(qvs, sv.x, oacc[jj * 4 + 0]);
      oacc[jj * 4 + 1] = fmaf(qvs, sv.y, oacc[jj * 4 + 1]);
      oacc[jj * 4 + 2] = fmaf(qvs, sv.z, oacc[jj * 4 + 2]);
      oacc[jj * 4 + 3] = fmaf(qvs, sv.w, oacc[jj * 4 + 3]);
    }
  }
  __syncthreads();
  // stage V (overwrites qt/kt)
  for (int base = 0; base < 8192; base += 1024) {
    const int idx = base + tid * 4;
    const int t = idx >> 7, v = idx & 127;
    *(float4*)&Vs[t * HV + v] = *(const float4*)&proj[(rowbase + t) * LDP + 2 * KD + h * HV + v];
  }
  __syncthreads();
  // o_intra = P @ V
  for (int j = 0; j < CHK; ++j) {
    const float pj = Pm[i][j];
#pragma unroll
    for (int jj = 0; jj < 8; ++jj) {
      const float4 vv = *(const float4*)&Vs[j * HV + vc * 4 + jj * 16];
      oacc[jj * 4 + 0] = fmaf(pj, vv.x, oacc[jj * 4 + 0]);
      oacc[jj * 4 + 1] = fmaf(pj, vv.y, oacc[jj * 4 + 1]);
      oacc[jj * 4 + 2] = fmaf(pj, vv.z, oacc[jj * 4 + 2]);
      oacc[jj * 4 + 3] = fmaf(pj, vv.w, oacc[jj * 4 + 3]);
    }
  }
  // epilogue: RMSNorm over HV (4 lanes share row i) * gnorm_w * silu(g)
  float ss = 0.f;
#pragma unroll
  for (int x = 0; x < 32; ++x) ss += oacc[x] * oacc[x];
  ss += __shfl_xor(ss, 1);
  ss += __shfl_xor(ss, 2);
  const float rn = rsqrtf(ss * (1.0f / 128.0f) + 1e-5f);
  const size_t row = rowbase + i;
  const float* gp = proj + row * LDP + 2 * VDIM + h * HV;  // g at col 1024
  float* op = og + row * (size_t)VDIM + h * HV;
#pragma unroll
  for (int jj = 0; jj < 8; ++jj) {
    const int v = vc * 4 + jj * 16;
    const float4 gv = *(const float4*)&gp[v];
    const float4 wv = *(const float4*)&gnw[v];
    float4 o;
    o.x = oacc[jj * 4 + 0] * rn * wv.x * (gv.x / (1.f + expf(-gv.x)));
    o.y = oacc[jj * 4 + 1] * rn * wv.y * (gv.y / (1.f + expf(-gv.y)));
    o.z = oacc[jj * 4 + 2] * rn * wv.z * (gv.z / (1.f + expf(-gv.z)));
    o.w = oacc[jj * 4 + 3] * rn * wv.w * (gv.w / (1.f + expf(-gv.w)));
    *(float4*)&op[v] = o;
  }
}

// ---------------------------------------------------------------------------
extern "C" void kernel_launch(void* const* d_in, const int* in_sizes, int n_in,
                              void* d_out, int out_size, void* d_ws, size_t ws_size,
                              hipStream_t stream) {
  const float* X    = (const float*)d_in[0];
  const float* Wq   = (const float*)d_in[1];
  const float* Wk   = (const float*)d_in[2];
  const float* Wv   = (const float*)d_in[3];
  const float* Wgk1 = (const float*)d_in[4];
  const float* Wgk2 = (const float*)d_in[5];
  const float* bgk2 = (const float*)d_in[6];
  const float* gnw  = (const float*)d_in[7];
  const float* Wg   = (const float*)d_in[8];
  const float* Wo   = (const float*)d_in[9];
  float* out = (float*)d_out;

  float* ws   = (float*)d_ws;
  float* proj = ws;                                    // 8192*1536
  float* g1   = proj + (size_t)MROWS * LDP;            // 8192*16
  float* gdec = g1 + (size_t)MROWS * 16;               // 8192*256
  float* dS   = gdec + (size_t)MROWS * KD;             // 16*32*64*128
  float* dvec = dS + (size_t)16 * NC * HK * HV;        // 16*32*64
  float* Sall = dvec + (size_t)16 * NC * HK;           // 16*32*64*128
  float* og   = Sall + (size_t)16 * NC * HK * HV;      // 8192*512

  const dim3 blk(256);
  // projections into proj (col offsets 0 / 256 / 512 / 1024)
  gemm_nt_f32<<<dim3(64, 2), blk, 0, stream>>>(X, Wq, proj + 0,    HIDD, LDP);
  gemm_nt_f32<<<dim3(64, 2), blk, 0, stream>>>(X, Wk, proj + 256,  HIDD, LDP);
  gemm_nt_f32<<<dim3(64, 4), blk, 0, stream>>>(X, Wv, proj + 512,  HIDD, LDP);
  gemm_nt_f32<<<dim3(64, 4), blk, 0, stream>>>(X, Wg, proj + 1024, HIDD, LDP);
  lowrank1<<<dim3(512), blk, 0, stream>>>(X, Wgk1, g1);
  gate_decay<<<dim3(MROWS), blk, 0, stream>>>(g1, Wgk2, bgk2, gdec);
  chunk_summary<<<dim3(NC, NH, BATCH), blk, 0, stream>>>(proj, gdec, dS, dvec);
  state_prop<<<dim3(16), blk, 0, stream>>>(dS, dvec, Sall);
  chunk_output<<<dim3(NC, NH, BATCH), blk, 0, stream>>>(proj, gdec, Sall, gnw, og);
  // final projection
  gemm_nt_f32<<<dim3(64, 4), blk, 0, stream>>>(og, Wo, out, VDIM, VDIM);
}

// Round 2
// 177.712 us; speedup vs baseline: 2.9896x; 2.9896x over previous
//
#include <hip/hip_runtime.h>
#include <hip/hip_bf16.h>

// Problem dims (fixed)
#define MROWS 8192      // B*T
#define HIDD  512
#define KD    256
#define VDIM  512
#define NH    4
#define HK    64
#define HV    128
#define TSEQ  2048
#define BATCH 4
#define NC    32        // number of chunks
#define CHK   64        // chunk length
#define LDP   1536      // proj row stride: q[0,256) k[256,512) v[512,1024) g[1024,1536)

typedef __attribute__((ext_vector_type(8))) short bf16x8;
typedef __attribute__((ext_vector_type(4))) float f32x4;
typedef __attribute__((address_space(1))) const void gas_t;
typedef __attribute__((address_space(3))) void las_t;

// ---------------------------------------------------------------------------
// fp32 -> bf16 cast of hidden_states
// ---------------------------------------------------------------------------
__global__ __launch_bounds__(256) void cast_x(const float* __restrict__ X,
                                              __hip_bfloat16* __restrict__ Xb) {
  const int i = (blockIdx.x * 256 + threadIdx.x) * 4;
  const float4 v = *(const float4*)(X + i);
  __hip_bfloat16 o[4] = {__float2bfloat16(v.x), __float2bfloat16(v.y),
                         __float2bfloat16(v.z), __float2bfloat16(v.w)};
  *(short4*)(Xb + i) = *(const short4*)o;
}

// ---------------------------------------------------------------------------
// Cast Wq,Wk,Wv,Wg into one contiguous [1536,512] bf16 matrix, then Wo after.
// dst element ranges: Wq [0,131072) Wk [131072,262144) Wv [262144,524288)
//                     Wg [524288,786432) Wo [786432,1048576)
// ---------------------------------------------------------------------------
__global__ __launch_bounds__(256) void cast_w(
    const float* __restrict__ Wq, const float* __restrict__ Wk,
    const float* __restrict__ Wv, const float* __restrict__ Wg,
    const float* __restrict__ Wo, __hip_bfloat16* __restrict__ dst) {
  const int i = (blockIdx.x * 256 + threadIdx.x) * 4;
  const float* src; int off;
  if (i < 131072)      { src = Wq; off = 0; }
  else if (i < 262144) { src = Wk; off = 131072; }
  else if (i < 524288) { src = Wv; off = 262144; }
  else if (i < 786432) { src = Wg; off = 524288; }
  else                 { src = Wo; off = 786432; }
  const float4 v = *(const float4*)(src + (i - off));
  __hip_bfloat16 o[4] = {__float2bfloat16(v.x), __float2bfloat16(v.y),
                         __float2bfloat16(v.z), __float2bfloat16(v.w)};
  *(short4*)(dst + i) = *(const short4*)o;
}

// ---------------------------------------------------------------------------
// bf16 MFMA GEMM: C[M,N](fp32, ldc) = A[M,K] @ W[N,K]^T, both bf16 row-major.
// 128x128 tile, BK=32, 256 thr (4 waves, each 64x64), 16x16x32 MFMA.
// global_load_lds width=16 staging; XOR-swizzled LDS (pre-swizzled source +
// swizzled ds_read) to break the row-stride-64B bank conflict.
// ---------------------------------------------------------------------------
__global__ __launch_bounds__(256) void gemm_bf16(
    const __hip_bfloat16* __restrict__ A, const __hip_bfloat16* __restrict__ Bw,
    float* __restrict__ C, int K, int ldc) {
  __shared__ __hip_bfloat16 As[128 * 32];
  __shared__ __hip_bfloat16 Bs[128 * 32];
  const int tid = threadIdx.x;
  const int wid = tid >> 6, lane = tid & 63;
  const int m0 = blockIdx.x * 128, n0 = blockIdx.y * 128;
  const int wm = (wid >> 1) * 64, wn = (wid & 1) * 64;
  f32x4 acc[4][4];
#pragma unroll
  for (int m = 0; m < 4; ++m)
#pragma unroll
    for (int n = 0; n < 4; ++n) acc[m][n] = (f32x4){0.f, 0.f, 0.f, 0.f};

  const int lrow = lane >> 2;        // 0..15 row within 16-row staging group
  const int lcb  = (lane & 3) * 16;  // byte col within 64B row

  for (int k0 = 0; k0 < K; k0 += 32) {
#pragma unroll
    for (int inst = 0; inst < 2; ++inst) {
      const int row = wid * 32 + inst * 16 + lrow;          // 0..127
      const int cb  = lcb ^ (((row >> 1) & 3) << 4);        // pre-swizzled src
      const __hip_bfloat16* ga = A  + (size_t)(m0 + row) * K + k0 + (cb >> 1);
      const __hip_bfloat16* gb = Bw + (size_t)(n0 + row) * K + k0 + (cb >> 1);
      __builtin_amdgcn_global_load_lds((gas_t*)ga,
          (las_t*)(As + (wid * 32 + inst * 16) * 32), 16, 0, 0);
      __builtin_amdgcn_global_load_lds((gas_t*)gb,
          (las_t*)(Bs + (wid * 32 + inst * 16) * 32), 16, 0, 0);
    }
    __syncthreads();
    const int kg = (lane >> 4) * 16;  // byte offset of this lane's k-group
    bf16x8 af[4], bfr[4];
#pragma unroll
    for (int m = 0; m < 4; ++m) {
      const int row = wm + m * 16 + (lane & 15);
      const int cb  = kg ^ (((row >> 1) & 3) << 4);
      af[m] = *(const bf16x8*)((const char*)As + row * 64 + cb);
    }
#pragma unroll
    for (int n = 0; n < 4; ++n) {
      const int row = wn + n * 16 + (lane & 15);
      const int cb  = kg ^ (((row >> 1) & 3) << 4);
      bfr[n] = *(const bf16x8*)((const char*)Bs + row * 64 + cb);
    }
#pragma unroll
    for (int m = 0; m < 4; ++m)
#pragma unroll
      for (int n = 0; n < 4; ++n)
        acc[m][n] = __builtin_amdgcn_mfma_f32_16x16x32_bf16(af[m], bfr[n], acc[m][n], 0, 0, 0);
    __syncthreads();
  }
  // epilogue: C/D layout col=lane&15, row=(lane>>4)*4+reg
  const int col = lane & 15;
  const int rb  = (lane >> 4) * 4;
#pragma unroll
  for (int m = 0; m < 4; ++m)
#pragma unroll
    for (int n = 0; n < 4; ++n) {
      float* cp = C + (size_t)(m0 + wm + m * 16 + rb) * ldc + n0 + wn + n * 16 + col;
      cp[0 * (size_t)ldc] = acc[m][n][0];
      cp[1 * (size_t)ldc] = acc[m][n][1];
      cp[2 * (size_t)ldc] = acc[m][n][2];
      cp[3 * (size_t)ldc] = acc[m][n][3];
    }
}

// ---------------------------------------------------------------------------
// g1 = X @ Wgk1^T   [8192,16], K=512.
// ---------------------------------------------------------------------------
__global__ __launch_bounds__(256) void lowrank1(
    const float* __restrict__ X, const float* __restrict__ W1,
    float* __restrict__ g1) {
  const int mrow = blockIdx.x * 16 + (threadIdx.x >> 4);
  const int col  = threadIdx.x & 15;
  const float* x = X + (size_t)mrow * HIDD;
  const float* w = W1 + (size_t)col * HIDD;
  float s = 0.f;
  for (int k = 0; k < HIDD; k += 4) {
    const float4 xv = *(const float4*)(x + k);
    const float4 wv = *(const float4*)(w + k);
    s += xv.x * wv.x + xv.y * wv.y + xv.z * wv.z + xv.w * wv.w;
  }
  g1[(size_t)mrow * 16 + col] = s;
}

// ---------------------------------------------------------------------------
// gdec[m,n] = log_sigmoid(g1[m,:] @ Wgk2[n,:] + b[n]) / 16.   [8192,256]
// ---------------------------------------------------------------------------
__global__ __launch_bounds__(256) void gate_decay(
    const float* __restrict__ g1, const float* __restrict__ W2,
    const float* __restrict__ bias, float* __restrict__ gdec) {
  const int m = blockIdx.x;
  const int n = threadIdx.x;
  const float* gr = g1 + (size_t)m * 16;
  const float* w  = W2 + (size_t)n * 16;
  float s = bias[n];
#pragma unroll
  for (int j4 = 0; j4 < 4; ++j4) {
    const float4 gv = *(const float4*)(gr + j4 * 4);
    const float4 wv = *(const float4*)(w + j4 * 4);
    s += gv.x * wv.x + gv.y * wv.y + gv.z * wv.z + gv.w * wv.w;
  }
  const float t = fabsf(s);
  const float ls = fminf(s, 0.f) - log1pf(expf(-t));
  gdec[(size_t)m * KD + n] = ls * (1.0f / 16.0f);
}

// ---------------------------------------------------------------------------
// Per-chunk summaries: dS[kk,v] = sum_t k[t,kk]*exp(B63[kk]-B_t[kk]) * V[t,v]
//                      dvec[kk] = exp(B63[kk]).   Grid (32,4,4), 256 thr.
// ---------------------------------------------------------------------------
__global__ __launch_bounds__(256) void chunk_summary(
    const float* __restrict__ proj, const float* __restrict__ gdec,
    float* __restrict__ dS, float* __restrict__ dvec) {
  __shared__ float kh[64][68];
  __shared__ float Vs[64 * HV];
  __shared__ float bl[64];
  const int c = blockIdx.x, h = blockIdx.y, b = blockIdx.z;
  const int bh = b * NH + h;
  const int tid = threadIdx.x;
  const size_t rowbase = (size_t)b * TSEQ + (size_t)c * CHK;
  for (int base = 0; base < 4096; base += 1024) {
    const int idx = base + tid * 4;
    const int t = idx >> 6, kk = idx & 63;
    *(float4*)&kh[t][kk] = *(const float4*)&gdec[(rowbase + t) * KD + h * HK + kk];
  }
  for (int base = 0; base < 8192; base += 1024) {
    const int idx = base + tid * 4;
    const int t = idx >> 7, v = idx & 127;
    *(float4*)&Vs[t * HV + v] = *(const float4*)&proj[(rowbase + t) * LDP + 2 * KD + h * HV + v];
  }
  __syncthreads();
  if (tid < 64) {
    float s = 0.f;
    for (int t = 0; t < CHK; ++t) { s += kh[t][tid]; kh[t][tid] = s; }
    bl[tid] = s;
    dvec[((size_t)bh * NC + c) * HK + tid] = expf(s);
  }
  __syncthreads();
  for (int base = 0; base < 4096; base += 1024) {
    const int idx = base + tid * 4;
    const int t = idx >> 6, kk = idx & 63;
    const float4 kv = *(const float4*)&proj[(rowbase + t) * LDP + KD + h * HK + kk];
    const float4 Bv = *(const float4*)&kh[t][kk];
    float4 rv;
    rv.x = kv.x * expf(bl[kk + 0] - Bv.x);
    rv.y = kv.y * expf(bl[kk + 1] - Bv.y);
    rv.z = kv.z * expf(bl[kk + 2] - Bv.z);
    rv.w = kv.w * expf(bl[kk + 3] - Bv.w);
    *(float4*)&kh[t][kk] = rv;
  }
  __syncthreads();
  const int kk = tid & 63;
  const int vg = (tid >> 6) * 32;
  float acc[32];
#pragma unroll
  for (int x = 0; x < 32; ++x) acc[x] = 0.f;
  for (int t = 0; t < CHK; ++t) {
    const float kv = kh[t][kk];
#pragma unroll
    for (int j = 0; j < 32; j += 4) {
      const float4 vv = *(const float4*)&Vs[t * HV + vg + j];
      acc[j + 0] = fmaf(kv, vv.x, acc[j + 0]);
      acc[j + 1] = fmaf(kv, vv.y, acc[j + 1]);
      acc[j + 2] = fmaf(kv, vv.z, acc[j + 2]);
      acc[j + 3] = fmaf(kv, vv.w, acc[j + 3]);
    }
  }
  float* outp = dS + (((size_t)bh * NC + c) * HK + kk) * HV + vg;
#pragma unroll
  for (int j = 0; j < 32; j += 4)
    *(float4*)(outp + j) = make_float4(acc[j], acc[j + 1], acc[j + 2], acc[j + 3]);
}

// ---------------------------------------------------------------------------
// Parallel inter-chunk state propagation: one thread per state element,
// 32 serial chunk steps, fully coalesced. 512 blocks x 256 thr.
// ---------------------------------------------------------------------------
__global__ __launch_bounds__(256) void state_prop(
    const float* __restrict__ dS, const float* __restrict__ dvec,
    float* __restrict__ Sall) {
  const int g  = blockIdx.x * 256 + threadIdx.x;  // 0..131071
  const int bh = g >> 13;
  const int el = g & 8191;
  float S = 0.f;
  size_t base = (size_t)bh * NC * 8192 + el;
  const float* dv = dvec + (size_t)bh * NC * HK + (el >> 7);
  for (int c = 0; c < NC; ++c) {
    Sall[base] = S;
    S = S * dv[(size_t)c * HK] + dS[base];
    base += 8192;
  }
}

// ---------------------------------------------------------------------------
// Per-chunk output: o = P@V + (q*scale*e^B)@S_prev, then fused per-head
// RMSNorm * gnorm_w * silu(g). Emits bf16 og. Grid (32,4,4), 256 threads.
// ---------------------------------------------------------------------------
__global__ __launch_bounds__(256) void chunk_output(
    const float* __restrict__ proj, const float* __restrict__ gdec,
    const float* __restrict__ Sall, const float* __restrict__ gnw,
    __hip_bfloat16* __restrict__ ogb) {
  __shared__ float smem[3 * 64 * 68];
  float (*qt)[68] = (float(*)[68])smem;
  float (*kt)[68] = (float(*)[68])(smem + 64 * 68);
  float (*Pm)[68] = (float(*)[68])(smem + 2 * 64 * 68);
  float* Vs = smem;  // [64][128] overlaps qt+kt
  const int c = blockIdx.x, h = blockIdx.y, b = blockIdx.z;
  const int bh = b * NH + h;
  const int tid = threadIdx.x;
  const size_t rowbase = (size_t)b * TSEQ + (size_t)c * CHK;
  for (int base = 0; base < 4096; base += 1024) {
    const int idx = base + tid * 4;
    const int t = idx >> 6, kk = idx & 63;
    *(float4*)&Pm[t][kk] = *(const float4*)&gdec[(rowbase + t) * KD + h * HK + kk];
  }
  __syncthreads();
  if (tid < 64) {
    float s = 0.f;
    for (int t = 0; t < CHK; ++t) { s += Pm[t][tid]; Pm[t][tid] = s; }
  }
  __syncthreads();
  for (int base = 0; base < 4096; base += 1024) {
    const int idx = base + tid * 4;
    const int t = idx >> 6, kk = idx & 63;
    const float4 qv = *(const float4*)&proj[(rowbase + t) * LDP + h * HK + kk];
    const float4 kv = *(const float4*)&proj[(rowbase + t) * LDP + KD + h * HK + kk];
    const float4 Bv = *(const float4*)&Pm[t][kk];
    qt[t][kk + 0] = qv.x * 0.125f * expf(Bv.x);
    qt[t][kk + 1] = qv.y * 0.125f * expf(Bv.y);
    qt[t][kk + 2] = qv.z * 0.125f * expf(Bv.z);
    qt[t][kk + 3] = qv.w * 0.125f * expf(Bv.w);
    kt[t][kk + 0] = kv.x * expf(-Bv.x);
    kt[t][kk + 1] = kv.y * expf(-Bv.y);
    kt[t][kk + 2] = kv.z * expf(-Bv.z);
    kt[t][kk + 3] = kv.w * expf(-Bv.w);
  }
  __syncthreads();
  const int i = tid >> 2;
  const int vc = tid & 3;
  float pv[16];
#pragma unroll
  for (int jj = 0; jj < 16; ++jj) pv[jj] = 0.f;
  for (int k0 = 0; k0 < CHK; k0 += 4) {
    const float4 qv = *(const float4*)&qt[i][k0];
#pragma unroll
    for (int jj = 0; jj < 16; ++jj) {
      const int j = vc + jj * 4;
      const float4 kv = *(const float4*)&kt[j][k0];
      pv[jj] += qv.x * kv.x + qv.y * kv.y + qv.z * kv.z + qv.w * kv.w;
    }
  }
#pragma unroll
  for (int jj = 0; jj < 16; ++jj) {
    const int j = vc + jj * 4;
    Pm[i][j] = (j <= i) ? pv[jj] : 0.f;
  }
  float oacc[32];
#pragma unroll
  for (int x = 0; x < 32; ++x) oacc[x] = 0.f;
  const float* Sp = Sall + ((size_t)bh * NC + c) * (HK * HV);
  for (int k = 0; k < HK; ++k) {
    const float qvs = qt[i][k];
#pragma unroll
    for (int jj = 0; jj < 8; ++jj) {
      const float4 sv = *(const float4*)&Sp[k * HV + vc * 4 + jj * 16];
      oacc[jj * 4 + 0] = fmaf(qvs, sv.x, oacc[jj * 4 + 0]);
      oacc[jj * 4 + 1] = fmaf(qvs, sv.y, oacc[jj * 4 + 1]);
      oacc[jj * 4 + 2] = fmaf(qvs, sv.z, oacc[jj * 4 + 2]);
      oacc[jj * 4 + 3] = fmaf(qvs, sv.w, oacc[jj * 4 + 3]);
    }
  }
  __syncthreads();
  for (int base = 0; base < 8192; base += 1024) {
    const int idx = base + tid * 4;
    const int t = idx >> 7, v = idx & 127;
    *(float4*)&Vs[t * HV + v] = *(const float4*)&proj[(rowbase + t) * LDP + 2 * KD + h * HV + v];
  }
  __syncthreads();
  for (int j = 0; j < CHK; ++j) {
    const float pj = Pm[i][j];
#pragma unroll
    for (int jj = 0; jj < 8; ++jj) {
      const float4 vv = *(const float4*)&Vs[j * HV + vc * 4 + jj * 16];
      oacc[jj * 4 + 0] = fmaf(pj, vv.x, oacc[jj * 4 + 0]);
      oacc[jj * 4 + 1] = fmaf(pj, vv.y, oacc[jj * 4 + 1]);
      oacc[jj * 4 + 2] = fmaf(pj, vv.z, oacc[jj * 4 + 2]);
      oacc[jj * 4 + 3] = fmaf(pj, vv.w, oacc[jj * 4 + 3]);
    }
  }
  float ss = 0.f;
#pragma unroll
  for (int x = 0; x < 32; ++x) ss += oacc[x] * oacc[x];
  ss += __shfl_xor(ss, 1);
  ss += __shfl_xor(ss, 2);
  const float rn = rsqrtf(ss * (1.0f / 128.0f) + 1e-5f);
  const size_t row = rowbase + i;
  const float* gp = proj + row * LDP + 2 * VDIM + h * HV;
  __hip_bfloat16* op = ogb + row * (size_t)VDIM + h * HV;
#pragma unroll
  for (int jj = 0; jj < 8; ++jj) {
    const int v = vc * 4 + jj * 16;
    const float4 gv = *(const float4*)&gp[v];
    const float4 wv = *(const float4*)&gnw[v];
    op[v + 0] = __float2bfloat16(oacc[jj * 4 + 0] * rn * wv.x * (gv.x / (1.f + expf(-gv.x))));
    op[v + 1] = __float2bfloat16(oacc[jj * 4 + 1] * rn * wv.y * (gv.y / (1.f + expf(-gv.y))));
    op[v + 2] = __float2bfloat16(oacc[jj * 4 + 2] * rn * wv.z * (gv.z / (1.f + expf(-gv.z))));
    op[v + 3] = __float2bfloat16(oacc[jj * 4 + 3] * rn * wv.w * (gv.w / (1.f + expf(-gv.w))));
  }
}

// ---------------------------------------------------------------------------
extern "C" void kernel_launch(void* const* d_in, const int* in_sizes, int n_in,
                              void* d_out, int out_size, void* d_ws, size_t ws_size,
                              hipStream_t stream) {
  const float* X    = (const float*)d_in[0];
  const float* Wq   = (const float*)d_in[1];
  const float* Wk   = (const float*)d_in[2];
  const float* Wv   = (const float*)d_in[3];
  const float* Wgk1 = (const float*)d_in[4];
  const float* Wgk2 = (const float*)d_in[5];
  const float* bgk2 = (const float*)d_in[6];
  const float* gnw  = (const float*)d_in[7];
  const float* Wg   = (const float*)d_in[8];
  const float* Wo   = (const float*)d_in[9];
  float* out = (float*)d_out;

  char* wsb = (char*)d_ws;
  float* proj = (float*)(wsb);                          // 50331648 B
  float* gdec = (float*)(wsb + 50331648);               //  8388608 B
  float* g1   = (float*)(wsb + 58720256);               //   524288 B
  float* dS   = (float*)(wsb + 59244544);               // 16777216 B
  float* dvec = (float*)(wsb + 76021760);               //   131072 B
  float* Sall = (float*)(wsb + 76152832);               // 16777216 B
  __hip_bfloat16* Xb   = (__hip_bfloat16*)(wsb + 92930048);   // 8388608 B
  __hip_bfloat16* Wcat = (__hip_bfloat16*)(wsb + 101318656);  // 1572864 B
  __hip_bfloat16* Wob  = (__hip_bfloat16*)(wsb + 102891520);  // 524288 B
  __hip_bfloat16* ogb  = (__hip_bfloat16*)dS;  // alias: dS dead before chunk_output

  const dim3 blk(256);
  cast_x<<<dim3(4096), blk, 0, stream>>>(X, Xb);
  cast_w<<<dim3(1024), blk, 0, stream>>>(Wq, Wk, Wv, Wg, Wo, Wcat);  // Wob follows Wcat
  // fused q|k|v|g projection: [8192,1536] = Xb @ Wcat^T
  gemm_bf16<<<dim3(64, 12), blk, 0, stream>>>(Xb, Wcat, proj, HIDD, LDP);
  lowrank1<<<dim3(512), blk, 0, stream>>>(X, Wgk1, g1);
  gate_decay<<<dim3(MROWS), blk, 0, stream>>>(g1, Wgk2, bgk2, gdec);
  chunk_summary<<<dim3(NC, NH, BATCH), blk, 0, stream>>>(proj, gdec, dS, dvec);
  state_prop<<<dim3(512), blk, 0, stream>>>(dS, dvec, Sall);
  chunk_output<<<dim3(NC, NH, BATCH), blk, 0, stream>>>(proj, gdec, Sall, gnw, ogb);
  gemm_bf16<<<dim3(64, 4), blk, 0, stream>>>(ogb, Wob, out, VDIM, VDIM);
}

// Round 4
// 148.347 us; speedup vs baseline: 3.5814x; 1.1979x over previous
//
#include <hip/hip_runtime.h>
#include <hip/hip_bf16.h>

// Problem dims (fixed)
#define MROWS 8192      // B*T
#define HIDD  512
#define KD    256
#define VDIM  512
#define NH    4
#define HK    64
#define HV    128
#define TSEQ  2048
#define BATCH 4
#define NC    32        // number of chunks
#define CHK   64        // chunk length
#define LDP   1536      // proj row stride: q[0,256) k[256,512) v[512,1024) g[1024,1536)

typedef __attribute__((ext_vector_type(8))) short bf16x8;
typedef __attribute__((ext_vector_type(4))) float f32x4;
typedef __attribute__((address_space(1))) const void gas_t;
typedef __attribute__((address_space(3))) void las_t;

#define MFMA(a, b, c) __builtin_amdgcn_mfma_f32_16x16x32_bf16(a, b, c, 0, 0, 0)

__device__ __forceinline__ void f2hl(float x, __hip_bfloat16& h, __hip_bfloat16& l) {
  h = __float2bfloat16(x);
  l = __float2bfloat16(x - __bfloat162float(h));
}

// ---------------------------------------------------------------------------
// fp32 -> bf16 cast of hidden_states
// ---------------------------------------------------------------------------
__global__ __launch_bounds__(256) void cast_x(const float* __restrict__ X,
                                              __hip_bfloat16* __restrict__ Xb) {
  const int i = (blockIdx.x * 256 + threadIdx.x) * 4;
  const float4 v = *(const float4*)(X + i);
  __hip_bfloat16 o[4] = {__float2bfloat16(v.x), __float2bfloat16(v.y),
                         __float2bfloat16(v.z), __float2bfloat16(v.w)};
  *(short4*)(Xb + i) = *(const short4*)o;
}

// ---------------------------------------------------------------------------
// Cast Wq,Wk,Wv,Wg into one contiguous [1536,512] bf16 matrix, then Wo after.
// ---------------------------------------------------------------------------
__global__ __launch_bounds__(256) void cast_w(
    const float* __restrict__ Wq, const float* __restrict__ Wk,
    const float* __restrict__ Wv, const float* __restrict__ Wg,
    const float* __restrict__ Wo, __hip_bfloat16* __restrict__ dst) {
  const int i = (blockIdx.x * 256 + threadIdx.x) * 4;
  const float* src; int off;
  if (i < 131072)      { src = Wq; off = 0; }
  else if (i < 262144) { src = Wk; off = 131072; }
  else if (i < 524288) { src = Wv; off = 262144; }
  else if (i < 786432) { src = Wg; off = 524288; }
  else                 { src = Wo; off = 786432; }
  const float4 v = *(const float4*)(src + (i - off));
  __hip_bfloat16 o[4] = {__float2bfloat16(v.x), __float2bfloat16(v.y),
                         __float2bfloat16(v.z), __float2bfloat16(v.w)};
  *(short4*)(dst + i) = *(const short4*)o;
}

// ---------------------------------------------------------------------------
// bf16 MFMA GEMM: C[M,N](fp32, ldc) = A[M,K] @ W[N,K]^T, both bf16 row-major.
// 128x128 tile, BK=32, 256 thr (4 waves), 16x16x32 MFMA, global_load_lds,
// XOR-swizzled LDS (pre-swizzled source + swizzled ds_read).
// ---------------------------------------------------------------------------
__global__ __launch_bounds__(256) void gemm_bf16(
    const __hip_bfloat16* __restrict__ A, const __hip_bfloat16* __restrict__ Bw,
    float* __restrict__ C, int K, int ldc) {
  __shared__ __hip_bfloat16 As[128 * 32];
  __shared__ __hip_bfloat16 Bs[128 * 32];
  const int tid = threadIdx.x;
  const int wid = tid >> 6, lane = tid & 63;
  const int m0 = blockIdx.x * 128, n0 = blockIdx.y * 128;
  const int wm = (wid >> 1) * 64, wn = (wid & 1) * 64;
  f32x4 acc[4][4];
#pragma unroll
  for (int m = 0; m < 4; ++m)
#pragma unroll
    for (int n = 0; n < 4; ++n) acc[m][n] = (f32x4){0.f, 0.f, 0.f, 0.f};

  const int lrow = lane >> 2;
  const int lcb  = (lane & 3) * 16;

  for (int k0 = 0; k0 < K; k0 += 32) {
#pragma unroll
    for (int inst = 0; inst < 2; ++inst) {
      const int row = wid * 32 + inst * 16 + lrow;
      const int cb  = lcb ^ (((row >> 1) & 3) << 4);
      const __hip_bfloat16* ga = A  + (size_t)(m0 + row) * K + k0 + (cb >> 1);
      const __hip_bfloat16* gb = Bw + (size_t)(n0 + row) * K + k0 + (cb >> 1);
      __builtin_amdgcn_global_load_lds((gas_t*)ga,
          (las_t*)(As + (wid * 32 + inst * 16) * 32), 16, 0, 0);
      __builtin_amdgcn_global_load_lds((gas_t*)gb,
          (las_t*)(Bs + (wid * 32 + inst * 16) * 32), 16, 0, 0);
    }
    __syncthreads();
    const int kg = (lane >> 4) * 16;
    bf16x8 af[4], bfr[4];
#pragma unroll
    for (int m = 0; m < 4; ++m) {
      const int row = wm + m * 16 + (lane & 15);
      const int cb  = kg ^ (((row >> 1) & 3) << 4);
      af[m] = *(const bf16x8*)((const char*)As + row * 64 + cb);
    }
#pragma unroll
    for (int n = 0; n < 4; ++n) {
      const int row = wn + n * 16 + (lane & 15);
      const int cb  = kg ^ (((row >> 1) & 3) << 4);
      bfr[n] = *(const bf16x8*)((const char*)Bs + row * 64 + cb);
    }
#pragma unroll
    for (int m = 0; m < 4; ++m)
#pragma unroll
      for (int n = 0; n < 4; ++n)
        acc[m][n] = MFMA(af[m], bfr[n], acc[m][n]);
    __syncthreads();
  }
  const int col = lane & 15;
  const int rb  = (lane >> 4) * 4;
#pragma unroll
  for (int m = 0; m < 4; ++m)
#pragma unroll
    for (int n = 0; n < 4; ++n) {
      float* cp = C + (size_t)(m0 + wm + m * 16 + rb) * ldc + n0 + wn + n * 16 + col;
      cp[0 * (size_t)ldc] = acc[m][n][0];
      cp[1 * (size_t)ldc] = acc[m][n][1];
      cp[2 * (size_t)ldc] = acc[m][n][2];
      cp[3 * (size_t)ldc] = acc[m][n][3];
    }
}

// ---------------------------------------------------------------------------
// g1 = X @ Wgk1^T   [8192,16], K=512.
// ---------------------------------------------------------------------------
__global__ __launch_bounds__(256) void lowrank1(
    const float* __restrict__ X, const float* __restrict__ W1,
    float* __restrict__ g1) {
  const int mrow = blockIdx.x * 16 + (threadIdx.x >> 4);
  const int col  = threadIdx.x & 15;
  const float* x = X + (size_t)mrow * HIDD;
  const float* w = W1 + (size_t)col * HIDD;
  float s = 0.f;
  for (int k = 0; k < HIDD; k += 4) {
    const float4 xv = *(const float4*)(x + k);
    const float4 wv = *(const float4*)(w + k);
    s += xv.x * wv.x + xv.y * wv.y + xv.z * wv.z + xv.w * wv.w;
  }
  g1[(size_t)mrow * 16 + col] = s;
}

// ---------------------------------------------------------------------------
// gdec[m,n] = log_sigmoid(g1[m,:] @ Wgk2[n,:] + b[n]) / 16.   [8192,256]
// ---------------------------------------------------------------------------
__global__ __launch_bounds__(256) void gate_decay(
    const float* __restrict__ g1, const float* __restrict__ W2,
    const float* __restrict__ bias, float* __restrict__ gdec) {
  const int m = blockIdx.x;
  const int n = threadIdx.x;
  const float* gr = g1 + (size_t)m * 16;
  const float* w  = W2 + (size_t)n * 16;
  float s = bias[n];
#pragma unroll
  for (int j4 = 0; j4 < 4; ++j4) {
    const float4 gv = *(const float4*)(gr + j4 * 4);
    const float4 wv = *(const float4*)(w + j4 * 4);
    s += gv.x * wv.x + gv.y * wv.y + gv.z * wv.z + gv.w * wv.w;
  }
  const float t = fabsf(s);
  const float ls = fminf(s, 0.f) - log1pf(expf(-t));
  gdec[(size_t)m * KD + n] = ls * (1.0f / 16.0f);
}

// ---------------------------------------------------------------------------
// Per-chunk summary via MFMA hi/lo:
//   dST[v][kk] = sum_t V[t][v] * k[t][kk]*exp(B63[kk]-B_t[kk])
//   dvec[kk]   = exp(B63[kk]).      Grid (32,4,4), 256 thr.
// ---------------------------------------------------------------------------
__global__ __launch_bounds__(256) void chunk_summary(
    const float* __restrict__ proj, const float* __restrict__ gdec,
    float* __restrict__ dST, float* __restrict__ dvec) {
  __shared__ float Bm[64][68];
  __shared__ float bl[64];
  __shared__ __hip_bfloat16 kTh[64][72], kTl[64][72];   // ktw^T [kk][t]
  __shared__ __hip_bfloat16 vTh[128][72], vTl[128][72]; // V^T  [v][t]
  const int c = blockIdx.x, h = blockIdx.y, b = blockIdx.z;
  const int bh = b * NH + h;
  const int tid = threadIdx.x;
  const size_t rowbase = (size_t)b * TSEQ + (size_t)c * CHK;
  for (int base = 0; base < 4096; base += 1024) {
    const int idx = base + tid * 4;
    const int t = idx >> 6, kk = idx & 63;
    *(float4*)&Bm[t][kk] = *(const float4*)&gdec[(rowbase + t) * KD + h * HK + kk];
  }
  __syncthreads();
  if (tid < 64) {
    float s = 0.f;
    for (int t = 0; t < CHK; ++t) { s += Bm[t][tid]; Bm[t][tid] = s; }
    bl[tid] = s;
    dvec[((size_t)bh * NC + c) * HK + tid] = expf(s);
  }
  __syncthreads();
  {
    const int t = tid >> 2;
    const int kk0 = (tid & 3) * 16;
    const float* kp = &proj[(rowbase + t) * LDP + KD + h * HK + kk0];
    float kv[16];
#pragma unroll
    for (int e4 = 0; e4 < 4; ++e4) *(float4*)&kv[e4 * 4] = *(const float4*)(kp + e4 * 4);
#pragma unroll
    for (int e = 0; e < 16; ++e) {
      const int kk = kk0 + e;
      const float val = kv[e] * expf(bl[kk] - Bm[t][kk]);
      f2hl(val, kTh[kk][t], kTl[kk][t]);
    }
  }
#pragma unroll
  for (int base = 0; base < 8192; base += 1024) {
    const int idx = base + tid * 4;
    const int t = idx >> 7, v = idx & 127;
    const float4 vv = *(const float4*)&proj[(rowbase + t) * LDP + 2 * KD + h * HV + v];
    f2hl(vv.x, vTh[v + 0][t], vTl[v + 0][t]);
    f2hl(vv.y, vTh[v + 1][t], vTl[v + 1][t]);
    f2hl(vv.z, vTh[v + 2][t], vTl[v + 2][t]);
    f2hl(vv.w, vTh[v + 3][t], vTl[v + 3][t]);
  }
  __syncthreads();
  const int wid = tid >> 6, lane = tid & 63;
  const int lr = lane & 15, lkb = (lane >> 4) * 8;
  f32x4 acc[2][4];
#pragma unroll
  for (int m = 0; m < 2; ++m)
#pragma unroll
    for (int n = 0; n < 4; ++n) acc[m][n] = (f32x4){0.f, 0.f, 0.f, 0.f};
#pragma unroll
  for (int ks = 0; ks < 2; ++ks) {
    const int kt = ks * 32 + lkb;
    bf16x8 ah[2], al[2], bh_[4], bl_[4];
#pragma unroll
    for (int m = 0; m < 2; ++m) {
      ah[m] = *(const bf16x8*)&vTh[wid * 32 + m * 16 + lr][kt];
      al[m] = *(const bf16x8*)&vTl[wid * 32 + m * 16 + lr][kt];
    }
#pragma unroll
    for (int n = 0; n < 4; ++n) {
      bh_[n] = *(const bf16x8*)&kTh[n * 16 + lr][kt];
      bl_[n] = *(const bf16x8*)&kTl[n * 16 + lr][kt];
    }
#pragma unroll
    for (int m = 0; m < 2; ++m)
#pragma unroll
      for (int n = 0; n < 4; ++n) {
        acc[m][n] = MFMA(ah[m], bh_[n], acc[m][n]);
        acc[m][n] = MFMA(ah[m], bl_[n], acc[m][n]);
        acc[m][n] = MFMA(al[m], bh_[n], acc[m][n]);
      }
  }
  const int rb = (lane >> 4) * 4;
  float* outb = dST + ((size_t)bh * NC + c) * 8192;
#pragma unroll
  for (int m = 0; m < 2; ++m)
#pragma unroll
    for (int n = 0; n < 4; ++n)
#pragma unroll
      for (int i = 0; i < 4; ++i)
        outb[(wid * 32 + m * 16 + rb + i) * 64 + n * 16 + lr] = acc[m][n][i];
}

// ---------------------------------------------------------------------------
// Inter-chunk state propagation (transposed layout), emits bf16 hi/lo S.
// One thread per state element, 32 serial chunk steps. 512 blocks x 256 thr.
// ---------------------------------------------------------------------------
__global__ __launch_bounds__(256) void state_prop(
    const float* __restrict__ dST, const float* __restrict__ dvec,
    __hip_bfloat16* __restrict__ ShT, __hip_bfloat16* __restrict__ SlT) {
  const int g  = blockIdx.x * 256 + threadIdx.x;  // 0..131071
  const int bh = g >> 13;
  const int el = g & 8191;        // el = v*64 + kk
  const int kk = el & 63;
  float S = 0.f;
  size_t base = (size_t)bh * NC * 8192 + el;
  const float* dv = dvec + (size_t)bh * NC * HK + kk;
  for (int c = 0; c < NC; ++c) {
    __hip_bfloat16 h, l;
    f2hl(S, h, l);
    ShT[base] = h; SlT[base] = l;
    S = S * dv[(size_t)c * HK] + dST[base];
    base += 8192;
  }
}

// ---------------------------------------------------------------------------
// Per-chunk output via MFMA hi/lo: o = P@V + (q*scale*e^B)@S_prev, fused
// per-head RMSNorm * gnorm_w * silu(g), emits bf16 og. Grid (32,4,4), 256 thr.
// ---------------------------------------------------------------------------
__global__ __launch_bounds__(256) void chunk_output(
    const float* __restrict__ proj, const float* __restrict__ gdec,
    const __hip_bfloat16* __restrict__ ShT, const __hip_bfloat16* __restrict__ SlT,
    const float* __restrict__ gnw, __hip_bfloat16* __restrict__ og) {
  __shared__ __align__(16) char smem[73984];
  __hip_bfloat16 (*qh)[72]  = (__hip_bfloat16(*)[72])(smem);           // [64][72]
  __hip_bfloat16 (*ql)[72]  = (__hip_bfloat16(*)[72])(smem + 9216);
  float        (*Bm)[68]    = (float(*)[68])(smem + 18432);            // transient
  __hip_bfloat16 (*Ph)[72]  = (__hip_bfloat16(*)[72])(smem + 18432);   // over Bm
  __hip_bfloat16 (*Pl)[72]  = (__hip_bfloat16(*)[72])(smem + 27648);
  __hip_bfloat16 (*kh)[72]  = (__hip_bfloat16(*)[72])(smem + 36864);   // transient
  __hip_bfloat16 (*kl)[72]  = (__hip_bfloat16(*)[72])(smem + 46080);
  __hip_bfloat16 (*vTh)[72] = (__hip_bfloat16(*)[72])(smem + 36864);   // over kh/kl
  __hip_bfloat16 (*vTl)[72] = (__hip_bfloat16(*)[72])(smem + 55296);
  const int c = blockIdx.x, h = blockIdx.y, b = blockIdx.z;
  const int bh = b * NH + h;
  const int tid = threadIdx.x;
  const size_t rowbase = (size_t)b * TSEQ + (size_t)c * CHK;
  // phase 1: gdec -> Bm, cumsum over t
  for (int base = 0; base < 4096; base += 1024) {
    const int idx = base + tid * 4;
    const int t = idx >> 6, kk = idx & 63;
    *(float4*)&Bm[t][kk] = *(const float4*)&gdec[(rowbase + t) * KD + h * HK + kk];
  }
  __syncthreads();
  if (tid < 64) {
    float s = 0.f;
    for (int t = 0; t < CHK; ++t) { s += Bm[t][tid]; Bm[t][tid] = s; }
  }
  __syncthreads();
  // phase 2: qt = q*scale*e^B (hi/lo), kt = k*e^{-B} (hi/lo)
  {
    const int t = tid >> 2;
    const int kk0 = (tid & 3) * 16;
    const float* qp = &proj[(rowbase + t) * LDP + h * HK + kk0];
    float qv[16], kv[16];
#pragma unroll
    for (int e4 = 0; e4 < 4; ++e4) {
      *(float4*)&qv[e4 * 4] = *(const float4*)(qp + e4 * 4);
      *(float4*)&kv[e4 * 4] = *(const float4*)(qp + KD + e4 * 4);
    }
#pragma unroll
    for (int e = 0; e < 16; ++e) {
      const int kk = kk0 + e;
      const float Bv = Bm[t][kk];
      f2hl(qv[e] * 0.125f * expf(Bv), qh[t][kk], ql[t][kk]);
      f2hl(kv[e] * expf(-Bv),         kh[t][kk], kl[t][kk]);
    }
  }
  __syncthreads();
  const int wid = tid >> 6, lane = tid & 63;
  const int lr = lane & 15, lkb = (lane >> 4) * 8;
  const int rb = (lane >> 4) * 4;
  // phase 3: P = qt @ kt^T (masked), -> Ph/Pl
  {
    f32x4 pacc[4];
#pragma unroll
    for (int n = 0; n < 4; ++n) pacc[n] = (f32x4){0.f, 0.f, 0.f, 0.f};
#pragma unroll
    for (int ks = 0; ks < 2; ++ks) {
      const int kt = ks * 32 + lkb;
      const bf16x8 aqh = *(const bf16x8*)&qh[wid * 16 + lr][kt];
      const bf16x8 aql = *(const bf16x8*)&ql[wid * 16 + lr][kt];
#pragma unroll
      for (int n = 0; n < 4; ++n) {
        const bf16x8 bkh = *(const bf16x8*)&kh[n * 16 + lr][kt];
        const bf16x8 bkl = *(const bf16x8*)&kl[n * 16 + lr][kt];
        pacc[n] = MFMA(aqh, bkh, pacc[n]);
        pacc[n] = MFMA(aqh, bkl, pacc[n]);
        pacc[n] = MFMA(aql, bkh, pacc[n]);
      }
    }
#pragma unroll
    for (int n = 0; n < 4; ++n)
#pragma unroll
      for (int i = 0; i < 4; ++i) {
        const int r = wid * 16 + rb + i;
        const int j = n * 16 + lr;
        const float v = (j <= r) ? pacc[n][i] : 0.f;
        f2hl(v, Ph[r][j], Pl[r][j]);
      }
  }
  __syncthreads();
  // phase 4: V^T hi/lo (overwrites kh/kl)
#pragma unroll
  for (int base = 0; base < 8192; base += 1024) {
    const int idx = base + tid * 4;
    const int t = idx >> 7, v = idx & 127;
    const float4 vv = *(const float4*)&proj[(rowbase + t) * LDP + 2 * KD + h * HV + v];
    f2hl(vv.x, vTh[v + 0][t], vTl[v + 0][t]);
    f2hl(vv.y, vTh[v + 1][t], vTl[v + 1][t]);
    f2hl(vv.z, vTh[v + 2][t], vTl[v + 2][t]);
    f2hl(vv.w, vTh[v + 3][t], vTl[v + 3][t]);
  }
  __syncthreads();
  // phase 5: o = qt@S^T + P@V
  f32x4 oacc[8];
#pragma unroll
  for (int n = 0; n < 8; ++n) oacc[n] = (f32x4){0.f, 0.f, 0.f, 0.f};
  const __hip_bfloat16* Sh = ShT + ((size_t)bh * NC + c) * 8192;
  const __hip_bfloat16* Sl = SlT + ((size_t)bh * NC + c) * 8192;
#pragma unroll
  for (int ks = 0; ks < 2; ++ks) {
    const int kt = ks * 32 + lkb;
    const bf16x8 aqh = *(const bf16x8*)&qh[wid * 16 + lr][kt];
    const bf16x8 aql = *(const bf16x8*)&ql[wid * 16 + lr][kt];
#pragma unroll
    for (int n = 0; n < 8; ++n) {
      const int v = n * 16 + lr;
      const bf16x8 sh = *(const bf16x8*)(Sh + v * 64 + kt);
      const bf16x8 sl = *(const bf16x8*)(Sl + v * 64 + kt);
      oacc[n] = MFMA(aqh, sh, oacc[n]);
      oacc[n] = MFMA(aqh, sl, oacc[n]);
      oacc[n] = MFMA(aql, sh, oacc[n]);
    }
  }
#pragma unroll
  for (int ks = 0; ks < 2; ++ks) {
    const int kt = ks * 32 + lkb;
    const bf16x8 aph = *(const bf16x8*)&Ph[wid * 16 + lr][kt];
    const bf16x8 apl = *(const bf16x8*)&Pl[wid * 16 + lr][kt];
#pragma unroll
    for (int n = 0; n < 8; ++n) {
      const bf16x8 bvh = *(const bf16x8*)&vTh[n * 16 + lr][kt];
      const bf16x8 bvl = *(const bf16x8*)&vTl[n * 16 + lr][kt];
      oacc[n] = MFMA(aph, bvh, oacc[n]);
      oacc[n] = MFMA(aph, bvl, oacc[n]);
      oacc[n] = MFMA(apl, bvh, oacc[n]);
    }
  }
  // epilogue: per-row RMSNorm over 128 v (reduce across 16-lane group)
  float ss[4] = {0.f, 0.f, 0.f, 0.f};
#pragma unroll
  for (int n = 0; n < 8; ++n)
#pragma unroll
    for (int i = 0; i < 4; ++i) ss[i] += oacc[n][i] * oacc[n][i];
#pragma unroll
  for (int i = 0; i < 4; ++i) {
    ss[i] += __shfl_xor(ss[i], 1);
    ss[i] += __shfl_xor(ss[i], 2);
    ss[i] += __shfl_xor(ss[i], 4);
    ss[i] += __shfl_xor(ss[i], 8);
  }
  float rn[4];
#pragma unroll
  for (int i = 0; i < 4; ++i) rn[i] = rsqrtf(ss[i] * (1.0f / 128.0f) + 1e-5f);
#pragma unroll
  for (int n = 0; n < 8; ++n) {
    const int v = n * 16 + lr;
    const float w = gnw[v];  // gnorm_w is [HV], broadcast across heads (bugfix)
#pragma unroll
    for (int i = 0; i < 4; ++i) {
      const size_t grow = rowbase + wid * 16 + rb + i;
      const float g = proj[grow * LDP + 2 * VDIM + h * HV + v];
      const float sil = g / (1.f + expf(-g));
      og[grow * VDIM + h * HV + v] = __float2bfloat16(oacc[n][i] * rn[i] * w * sil);
    }
  }
}

// ---------------------------------------------------------------------------
extern "C" void kernel_launch(void* const* d_in, const int* in_sizes, int n_in,
                              void* d_out, int out_size, void* d_ws, size_t ws_size,
                              hipStream_t stream) {
  const float* X    = (const float*)d_in[0];
  const float* Wq   = (const float*)d_in[1];
  const float* Wk   = (const float*)d_in[2];
  const float* Wv   = (const float*)d_in[3];
  const float* Wgk1 = (const float*)d_in[4];
  const float* Wgk2 = (const float*)d_in[5];
  const float* bgk2 = (const float*)d_in[6];
  const float* gnw  = (const float*)d_in[7];
  const float* Wg   = (const float*)d_in[8];
  const float* Wo   = (const float*)d_in[9];
  float* out = (float*)d_out;

  char* wsb = (char*)d_ws;
  float* proj = (float*)(wsb);                              // 50331648 B
  float* gdec = (float*)(wsb + 50331648);                   //  8388608 B
  float* g1   = (float*)(wsb + 58720256);                   //   524288 B
  float* dST  = (float*)(wsb + 59244544);                   // 16777216 B
  float* dvec = (float*)(wsb + 76021760);                   //   131072 B
  __hip_bfloat16* ShT  = (__hip_bfloat16*)(wsb + 76152832); //  8388608 B
  __hip_bfloat16* SlT  = (__hip_bfloat16*)(wsb + 84541440); //  8388608 B
  __hip_bfloat16* Xb   = (__hip_bfloat16*)(wsb + 92930048); //  8388608 B
  __hip_bfloat16* Wcat = (__hip_bfloat16*)(wsb + 101318656);//  2097152 B (incl Wo)
  __hip_bfloat16* Wob  = Wcat + 786432;
  __hip_bfloat16* ogb  = (__hip_bfloat16*)dST;  // alias: dST dead before chunk_output

  const dim3 blk(256);
  cast_x<<<dim3(4096), blk, 0, stream>>>(X, Xb);
  cast_w<<<dim3(1024), blk, 0, stream>>>(Wq, Wk, Wv, Wg, Wo, Wcat);
  gemm_bf16<<<dim3(64, 12), blk, 0, stream>>>(Xb, Wcat, proj, HIDD, LDP);
  lowrank1<<<dim3(512), blk, 0, stream>>>(X, Wgk1, g1);
  gate_decay<<<dim3(MROWS), blk, 0, stream>>>(g1, Wgk2, bgk2, gdec);
  chunk_summary<<<dim3(NC, NH, BATCH), blk, 0, stream>>>(proj, gdec, dST, dvec);
  state_prop<<<dim3(512), blk, 0, stream>>>(dST, dvec, ShT, SlT);
  chunk_output<<<dim3(NC, NH, BATCH), blk, 0, stream>>>(proj, gdec, ShT, SlT, gnw, ogb);
  gemm_bf16<<<dim3(64, 4), blk, 0, stream>>>(ogb, Wob, out, VDIM, VDIM);
}